// Round 2
// baseline (6662.994 us; speedup 1.0000x reference)
//
#include <hip/hip_runtime.h>

#define ALPHA_F 0.1f
#define NITER 20

// ---------------------------------------------------------------------------
// Cl(3,0) sign: e_a * e_c = SG * e_{a^c};  BWD adds reversion sign of blade c.
// ---------------------------------------------------------------------------
template <bool BWD>
__device__ __host__ constexpr float SG(int a, int c) {
  const int a1 = (a >> 1) & 1, a2 = (a >> 2) & 1;
  const int c0 = c & 1, c1 = (c >> 1) & 1;
  int p = (c0 & (a1 ^ a2)) ^ (c1 & a2);
  if (BWD) {
    const int r = (c & 1) + ((c >> 1) & 1) + ((c >> 2) & 1);
    p ^= (r >= 2) ? 1 : 0;
  }
  return p ? -1.0f : 1.0f;
}

// ---------------------------------------------------------------------------
// Generalized split-K gp-GEMM with fused deterministic last-block reduce.
//   out[b,m,k] = scale * sum_n sum_{a,c} C[a,c,k]*A[b,n,a]*W(m,n,c) (+ add)
//   A addr: base*(b*a1bs + n*a1ns) + a ; n >= nsplit reads A1b with n-nsplit.
//   W addr: FWD W[m*wstr + n*8 + c] ; BWD W[n*wstr + m*8 + c] (sign *= REV[c]).
//   Two independent "roles" (param sets) per dispatch: bid < NA -> ga else gb.
// ---------------------------------------------------------------------------
struct GP {
  const float* A1; int a1bs, a1ns;
  const float* A1b; int a2bs, a2ns; int nsplit;
  const float* W; int wstr;
  float* P; int* ctr;
  float* out; int obs, oms;
  const float* add; int adbs, adms;
  float scale;
  int mtiles, nsl, nch, btiles;
  int M8, Btot;
};

template <bool BWD>
__global__ __launch_bounds__(256) void gp_pair(GP ga, GP gb, int NA) {
  __shared__ float At[64 * 132];
  __shared__ float Wt[16 * 132];
  __shared__ int islast;

  const GP g = (blockIdx.x < (unsigned)NA) ? ga : gb;
  const int r = (blockIdx.x < (unsigned)NA) ? blockIdx.x : blockIdx.x - NA;

  const int tid = threadIdx.x;
  const int mt = r % g.mtiles;
  const int t2 = r / g.mtiles;
  const int sl = t2 % g.nsl;
  const int bt = t2 / g.nsl;
  const int m0 = mt * 16;
  const int b0 = bt * 64;
  const int ml = tid & 7;
  const int bg = tid >> 3;

  float acc[2][2][8];
#pragma unroll
  for (int i = 0; i < 2; ++i)
#pragma unroll
    for (int j = 0; j < 2; ++j)
#pragma unroll
      for (int k = 0; k < 8; ++k) acc[i][j][k] = 0.0f;

  for (int ch = 0; ch < g.nch; ++ch) {
    const int n0 = (sl * g.nch + ch) * 16;

    // ---- stage A tile: 64 rows x (16n x 8a) ----
    for (int j = tid; j < 2048; j += 256) {
      const int b = j >> 5;
      const int c4 = (j & 31) * 4;
      const int nl = c4 >> 3, rem = c4 & 7;
      const int n = n0 + nl;
      const float* base;
      int bs, ns, nn;
      if (n < g.nsplit) { base = g.A1; bs = g.a1bs; ns = g.a1ns; nn = n; }
      else { base = g.A1b; bs = g.a2bs; ns = g.a2ns; nn = n - g.nsplit; }
      const float4 v =
          *(const float4*)(base + (size_t)(b0 + b) * bs + (size_t)nn * ns + rem);
      *(float4*)&At[b * 132 + c4] = v;
    }
    // ---- stage W tile: 16m x (16n x 8c) ----
    if (!BWD) {
      for (int j = tid; j < 512; j += 256) {
        const int rr = j >> 5, c4 = (j & 31) * 4;
        const float4 v =
            *(const float4*)(g.W + (size_t)(m0 + rr) * g.wstr + n0 * 8 + c4);
        *(float4*)&Wt[rr * 132 + c4] = v;
      }
    } else {
      for (int j = tid; j < 512; j += 256) {
        const int rr = j >> 5, c4j = j & 31;
        const float4 v = *(const float4*)(g.W + (size_t)(n0 + rr) * g.wstr +
                                          (m0 + (c4j >> 1)) * 8 + (c4j & 1) * 4);
        *(float4*)&Wt[(c4j >> 1) * 132 + rr * 8 + (c4j & 1) * 4] = v;
      }
    }
    __syncthreads();

#pragma unroll 2
    for (int n = 0; n < 16; ++n) {
      float wv[2][8];
#pragma unroll
      for (int mm = 0; mm < 2; ++mm) {
        const float4 u0 = *(const float4*)&Wt[(ml + mm * 8) * 132 + n * 8];
        const float4 u1 = *(const float4*)&Wt[(ml + mm * 8) * 132 + n * 8 + 4];
        wv[mm][0] = u0.x; wv[mm][1] = u0.y; wv[mm][2] = u0.z; wv[mm][3] = u0.w;
        wv[mm][4] = u1.x; wv[mm][5] = u1.y; wv[mm][6] = u1.z; wv[mm][7] = u1.w;
      }
#pragma unroll
      for (int bb = 0; bb < 2; ++bb) {
        const int b = bg + bb * 32;
        float av[8];
        const float4 a0 = *(const float4*)&At[b * 132 + n * 8];
        const float4 a1 = *(const float4*)&At[b * 132 + n * 8 + 4];
        av[0] = a0.x; av[1] = a0.y; av[2] = a0.z; av[3] = a0.w;
        av[4] = a1.x; av[5] = a1.y; av[6] = a1.z; av[7] = a1.w;
#pragma unroll
        for (int mm = 0; mm < 2; ++mm)
#pragma unroll
          for (int a = 0; a < 8; ++a)
#pragma unroll
            for (int c = 0; c < 8; ++c)
              acc[bb][mm][a ^ c] =
                  fmaf(SG<BWD>(a, c) * av[a], wv[mm][c], acc[bb][mm][a ^ c]);
      }
    }
    __syncthreads();
  }

  // ---- write partials ----
  {
    float* Po = g.P + ((size_t)sl * g.Btot + b0) * g.M8;
#pragma unroll
    for (int bb = 0; bb < 2; ++bb)
#pragma unroll
      for (int mm = 0; mm < 2; ++mm) {
        float* q = Po + (size_t)(bg + bb * 32) * g.M8 + (m0 + ml + mm * 8) * 8;
        float4 v0 = {acc[bb][mm][0], acc[bb][mm][1], acc[bb][mm][2], acc[bb][mm][3]};
        float4 v1 = {acc[bb][mm][4], acc[bb][mm][5], acc[bb][mm][6], acc[bb][mm][7]};
        *(float4*)q = v0;
        *(float4*)(q + 4) = v1;
      }
  }

  // ---- last-block deterministic reduce ----
  __threadfence();
  __syncthreads();
  if (tid == 0) {
    const int c = atomicAdd(&g.ctr[bt * g.mtiles + mt], 1);
    islast = (c == g.nsl - 1);
    if (islast) g.ctr[bt * g.mtiles + mt] = 0;
  }
  __syncthreads();
  if (!islast) return;
  __threadfence();

  size_t off[8];
  float4 s[8];
#pragma unroll
  for (int u = 0; u < 8; ++u) {
    const int j = tid + u * 256;
    const int b = j >> 5, rr = j & 31;
    const int m = rr >> 1, k4 = (rr & 1) * 4;
    off[u] = (size_t)(b0 + b) * g.M8 + (m0 + m) * 8 + k4;
    s[u] = float4{0.f, 0.f, 0.f, 0.f};
  }
  const size_t PB = (size_t)g.Btot * g.M8;
  for (int sidx = 0; sidx < g.nsl; ++sidx) {
#pragma unroll
    for (int u = 0; u < 8; ++u) {
      const float4 v = *(const float4*)(g.P + (size_t)sidx * PB + off[u]);
      s[u].x += v.x; s[u].y += v.y; s[u].z += v.z; s[u].w += v.w;
    }
  }
#pragma unroll
  for (int u = 0; u < 8; ++u) {
    const int j = tid + u * 256;
    const int b = j >> 5, rr = j & 31;
    const int m = rr >> 1, k4 = (rr & 1) * 4;
    float4 o = {g.scale * s[u].x, g.scale * s[u].y, g.scale * s[u].z,
                g.scale * s[u].w};
    if (g.add) {
      const float* ap = g.add + (size_t)(b0 + b) * g.adbs + (m0 + m) * g.adms + k4;
      const float4 av = *(const float4*)ap;
      o.x += av.x; o.y += av.y; o.z += av.z; o.w += av.w;
    }
    *(float4*)(g.out + (size_t)(b0 + b) * g.obs + (m0 + m) * g.oms + k4) = o;
  }
}

// ---------------------------------------------------------------------------
// init: out0 = x ; Z0 = 0 ; Wcat w2T-part pack (alpha * REV) ; ctr = 0
// ---------------------------------------------------------------------------
__global__ __launch_bounds__(256) void init_k(const float* __restrict__ x,
                                              const float* __restrict__ w2,
                                              float* __restrict__ out0,
                                              float* __restrict__ Z0,
                                              float* __restrict__ Wcat,
                                              int* __restrict__ ctr) {
  const int i = blockIdx.x * 256 + threadIdx.x;  // float4 index
  if (i < 32768) {
    ((float4*)out0)[i] = ((const float4*)x)[i];
  } else if (i < 131072) {
    ((float4*)Z0)[i - 32768] = float4{0.f, 0.f, 0.f, 0.f};
  } else if (i < 393216) {
    const int u = i - 131072;
    const int c4 = u & 1;
    const int m = (u >> 1) & 511;
    const int n = u >> 10;
    float4 v = *(const float4*)(w2 + (size_t)m * 2048 + n * 8 + c4 * 4);
    // REV = [+,+,+,-,+,-,-,-] ; scaled by ALPHA
    if (c4 == 0) { v.x *= ALPHA_F; v.y *= ALPHA_F; v.z *= ALPHA_F; v.w *= -ALPHA_F; }
    else { v.x *= ALPHA_F; v.y *= -ALPHA_F; v.z *= -ALPHA_F; v.w *= -ALPHA_F; }
    *(float4*)(Wcat + (size_t)n * 6144 + (256 + m) * 8 + c4 * 4) = v;
  } else if (i < 393728) {
    ((float4*)ctr)[i - 393216] = float4{0.f, 0.f, 0.f, 0.f};
  }
}

// fixup: Z1.S1 = c1 ; v1 diag += 1 ; Wcat diag += 1
__global__ __launch_bounds__(256) void fixup_k(const float* __restrict__ c1buf,
                                               float* __restrict__ Z1,
                                               float* __restrict__ v1,
                                               float* __restrict__ Wcat) {
  const int i = blockIdx.x * 256 + threadIdx.x;  // 65536 float4s
  const int b = i >> 10, col = i & 1023;
  const float4 v = ((const float4*)c1buf)[i];
  *(float4*)(Z1 + (size_t)b * 6144 + 2048 + col * 4) = v;
  if (i < 512) v1[(size_t)i * 4096 + i * 8] += 1.0f;
  if (i < 256) Wcat[(size_t)i * 6144 + i * 8] += 1.0f;
}

extern "C" void kernel_launch(void* const* d_in, const int* in_sizes, int n_in,
                              void* d_out, int out_size, void* d_ws, size_t ws_size,
                              hipStream_t stream) {
  const float* x = (const float*)d_in[0];    // (64, 256, 8)
  const float* w1 = (const float*)d_in[1];   // (256, 512, 8)
  const float* w2 = (const float*)d_in[2];   // (512, 256, 8)

  float* out0 = (float*)d_out;
  float* out1 = out0 + 131072;               // S1_20 (64,512,8)
  float* out2 = out1 + 262144;               // S2_20 (64,256,8)

  float* ws = (float*)d_ws;
  float* arena = ws;                         // 25,165,824 floats
  float* P1 = arena;                         // gemm1 partials 32*64*4096
  float* P2 = arena + 8388608;               // gemm2 partials 48*64*2048
  float* Pv1 = arena;                        // v1 partials 8*512*4096
  float* Pv2 = arena + 16777216;             // v2 partials 16*256*2048
  float* Pc1 = arena;                        // c1 partials 16*64*4096
  float* v1buf = ws + 25165824;              // (512,512,8)
  float* Wcat = v1buf + 2097152;             // (256,768,8)
  float* c1buf = Wcat + 1572864;             // (64,512,8)
  float* Z0 = c1buf + 262144;                // (64,6144): [S2 | S1]
  float* Z1 = Z0 + 393216;
  int* ctr = (int*)(Z1 + 393216);            // 2048 ints

  // D1: init
  init_k<<<1538, 256, 0, stream>>>(x, w2, out0, Z0, Wcat, ctr);

  // D2: pair(v1, v2)  -- composite operators V1, V2 (scaled by -alpha)
  GP gv1, gv2;
  gv1.A1 = w1; gv1.a1bs = 8; gv1.a1ns = 4096;
  gv1.A1b = w1; gv1.a2bs = 8; gv1.a2ns = 4096; gv1.nsplit = 1 << 30;
  gv1.W = w1; gv1.wstr = 4096;
  gv1.P = Pv1; gv1.ctr = ctr;
  gv1.out = v1buf; gv1.obs = 8; gv1.oms = 4096;
  gv1.add = nullptr; gv1.adbs = 0; gv1.adms = 0;
  gv1.scale = -ALPHA_F;
  gv1.mtiles = 32; gv1.nsl = 8; gv1.nch = 2; gv1.btiles = 8;
  gv1.M8 = 4096; gv1.Btot = 512;

  gv2.A1 = w2; gv2.a1bs = 8; gv2.a1ns = 2048;
  gv2.A1b = w2; gv2.a2bs = 8; gv2.a2ns = 2048; gv2.nsplit = 1 << 30;
  gv2.W = w2; gv2.wstr = 2048;
  gv2.P = Pv2; gv2.ctr = ctr + 1024;
  gv2.out = Wcat; gv2.obs = 8; gv2.oms = 6144;
  gv2.add = nullptr; gv2.adbs = 0; gv2.adms = 0;
  gv2.scale = -ALPHA_F;
  gv2.mtiles = 16; gv2.nsl = 16; gv2.nch = 2; gv2.btiles = 4;
  gv2.M8 = 2048; gv2.Btot = 256;
  gp_pair<true><<<2048 + 1024, 256, 0, stream>>>(gv1, gv2, 2048);

  // D3: c1 = alpha * gp(x, w1T)
  GP gc1;
  gc1.A1 = x; gc1.a1bs = 2048; gc1.a1ns = 8;
  gc1.A1b = x; gc1.a2bs = 2048; gc1.a2ns = 8; gc1.nsplit = 1 << 30;
  gc1.W = w1; gc1.wstr = 4096;
  gc1.P = Pc1; gc1.ctr = ctr;
  gc1.out = c1buf; gc1.obs = 4096; gc1.oms = 8;
  gc1.add = nullptr; gc1.adbs = 0; gc1.adms = 0;
  gc1.scale = ALPHA_F;
  gc1.mtiles = 32; gc1.nsl = 16; gc1.nch = 1; gc1.btiles = 1;
  gc1.M8 = 4096; gc1.Btot = 64;
  gp_pair<true><<<512, 256, 0, stream>>>(gc1, gc1, 512);

  // D4: fixup (identity diagonals; Z1.S1 = S1_1 = c1)
  fixup_k<<<256, 256, 0, stream>>>(c1buf, Z1, v1buf, Wcat);

  // D5..D23: CD_t = { gemm2_t , gemm1_{t+1} },  t = 0..18
  float* Z[2] = {Z0, Z1};
  for (int t = 0; t <= 18; ++t) {
    const int cur = t & 1, nxt = cur ^ 1;
    GP g2, g1;
    // gemm2_t: S2_{t+1} = gp([S2_t | S1_{t+1}], Wcat)
    g2.A1 = Z[cur]; g2.a1bs = 6144; g2.a1ns = 8;
    g2.A1b = Z[nxt] + 2048; g2.a2bs = 6144; g2.a2ns = 8; g2.nsplit = 256;
    g2.W = Wcat; g2.wstr = 6144;
    g2.P = P2; g2.ctr = ctr;
    g2.out = Z[nxt]; g2.obs = 6144; g2.oms = 8;
    g2.add = nullptr; g2.adbs = 0; g2.adms = 0;
    g2.scale = 1.0f;
    g2.mtiles = 16; g2.nsl = 48; g2.nch = 1; g2.btiles = 1;
    g2.M8 = 2048; g2.Btot = 64;
    // gemm1_{t+1}: S1_{t+2} = gp(S1_{t+1}, v1~) + c1
    const bool last1 = (t + 1 == 19);
    g1.A1 = Z[nxt] + 2048; g1.a1bs = 6144; g1.a1ns = 8;
    g1.A1b = g1.A1; g1.a2bs = 6144; g1.a2ns = 8; g1.nsplit = 1 << 30;
    g1.W = v1buf; g1.wstr = 4096;
    g1.P = P1; g1.ctr = ctr + 1024;
    g1.out = last1 ? out1 : (Z[cur] + 2048);
    g1.obs = last1 ? 4096 : 6144; g1.oms = 8;
    g1.add = c1buf; g1.adbs = 4096; g1.adms = 8;
    g1.scale = 1.0f;
    g1.mtiles = 32; g1.nsl = 32; g1.nch = 1; g1.btiles = 1;
    g1.M8 = 4096; g1.Btot = 64;
    gp_pair<false><<<768 + 1024, 256, 0, stream>>>(g2, g1, 768);
  }

  // D24: gemm2_19 -> out2
  {
    GP g2;
    g2.A1 = Z[1]; g2.a1bs = 6144; g2.a1ns = 8;
    g2.A1b = out1; g2.a2bs = 4096; g2.a2ns = 8; g2.nsplit = 256;
    g2.W = Wcat; g2.wstr = 6144;
    g2.P = P2; g2.ctr = ctr;
    g2.out = out2; g2.obs = 2048; g2.oms = 8;
    g2.add = nullptr; g2.adbs = 0; g2.adms = 0;
    g2.scale = 1.0f;
    g2.mtiles = 16; g2.nsl = 48; g2.nch = 1; g2.btiles = 1;
    g2.M8 = 2048; g2.Btot = 64;
    gp_pair<false><<<768, 256, 0, stream>>>(g2, g2, 768);
  }
}

// Round 3
// 1920.907 us; speedup vs baseline: 3.4687x; 3.4687x over previous
//
#include <hip/hip_runtime.h>

typedef unsigned short u16;
typedef __attribute__((ext_vector_type(4))) float f32x4;
typedef __attribute__((ext_vector_type(8))) __bf16 bf16x8;
typedef __attribute__((ext_vector_type(8))) u16 u16x8;

#define ALPHA_F 0.1f

// Cl(3,0) forward sign for e_a * e_c -> e_{a^c}
__device__ __forceinline__ float sgf(int a, int c) {
  int a1 = (a >> 1) & 1, a2 = (a >> 2) & 1, c0 = c & 1, c1 = (c >> 1) & 1;
  int p = (c0 & (a1 ^ a2)) ^ (c1 & a2);
  return p ? -1.f : 1.f;
}
// forward sign * reversion sign of blade c
__device__ __forceinline__ float sgr(int a, int c) {
  int a1 = (a >> 1) & 1, a2 = (a >> 2) & 1, c0 = c & 1, c1 = (c >> 1) & 1;
  int p = (c0 & (a1 ^ a2)) ^ (c1 & a2);
  int r = (c & 1) + ((c >> 1) & 1) + ((c >> 2) & 1);
  p ^= (r >= 2) ? 1 : 0;
  return p ? -1.f : 1.f;
}
__device__ __forceinline__ u16 bf_rnd(float f) {  // fp32 -> bf16 rne
  unsigned u = __float_as_uint(f);
  return (u16)((u + 0x7FFFu + ((u >> 16) & 1u)) >> 16);
}
__device__ __forceinline__ float bf_val(u16 h) {
  return __uint_as_float(((unsigned)h) << 16);
}
__device__ __forceinline__ void gl16(const u16* g, u16* l) {
  __builtin_amdgcn_global_load_lds(
      (const __attribute__((address_space(1))) void*)g,
      (__attribute__((address_space(3))) void*)l, 16, 0, 0);
}
__device__ __forceinline__ f32x4 mf(bf16x8 a, bf16x8 b, f32x4 c) {
  return __builtin_amdgcn_mfma_f32_16x16x32_bf16(a, b, c, 0, 0, 0);
}

// ---------------------------------------------------------------------------
// Generic 64xN MFMA GEMM, 3-pass split-bf16: out = Ahi*Whi + Alo*Whi + Ahi*Wlo
// A packed [mt][chunk][64 rows][8], W packed [panel][chunk][64 cols][8],
// chunk = 8 contiguous k. BK=32 (4 chunks)/step, double-buffered LDS.
// Optional K-split with deterministic counter-gated last-block reduce.
// Epilogues: ctype0 = (+addC) -> outF fp32 and/or Z hi/lo bf16 A-format;
//            ctype1 = fused Wcat-top pack (sign/permute/diag/split).
// ---------------------------------------------------------------------------
struct Role {
  const u16* Ahi; const u16* Alo;
  const u16* Whi; const u16* Wlo;
  float* P; int* ctr;
  u16* Zhi; u16* Zlo;
  float* outF; const float* addC;
  int kchA;    // A mtile stride (chunks)
  int pstr;    // W panel stride (chunks)
  int mtiles, npan, ksl, kcpsl;
  int zoff, ncF, ctype, ctrb;
};

__global__ __launch_bounds__(256) void gemm3(Role r0, Role r1, Role r2,
                                             int n0, int n1) {
  __shared__ u16 st[2][4][2048];  // [dbuf][Ahi,Alo,Whi,Wlo][4KB]
  __shared__ int islast;
  float* LDSf = (float*)&st[0][0][0];  // 64x68 fp32, aliases st (post-loop)

  const int bid = blockIdx.x;
  Role R; int rr;
  if (bid < n0) { R = r0; rr = bid; }
  else if (bid < n0 + n1) { R = r1; rr = bid - n0; }
  else { R = r2; rr = bid - n0 - n1; }

  const int tid = threadIdx.x;
  const int wv = tid >> 6, ln = tid & 63;
  const int lg = ln >> 4, lr = ln & 15;

  const int mt = rr % R.mtiles;
  const int rem = rr / R.mtiles;
  const int p = rem % R.npan;
  const int sl = rem / R.npan;

  const int ca0 = mt * R.kchA + sl * R.kcpsl;
  const int cw0 = p * R.pstr + sl * R.kcpsl;
  const bool three = (R.Wlo != nullptr);

  f32x4 acc[4];
#pragma unroll
  for (int i = 0; i < 4; ++i) acc[i] = f32x4{0.f, 0.f, 0.f, 0.f};

  auto STAGE = [&](int db, int cA, int cW) {
    const u16* src;
    if (wv == 0) src = R.Ahi + (size_t)cA * 512;
    else if (wv == 1) src = R.Alo + (size_t)cA * 512;
    else if (wv == 2) src = R.Whi + (size_t)cW * 512;
    else { if (!three) return; src = R.Wlo + (size_t)cW * 512; }
    u16* dst = &st[db][wv][0];
#pragma unroll
    for (int i = 0; i < 4; ++i) gl16(src + i * 512 + ln * 8, dst + i * 512);
  };

  const int nst = R.kcpsl >> 2;
  STAGE(0, ca0, cw0);
  int db = 0;
  for (int s = 0; s < nst; ++s) {
    asm volatile("s_waitcnt vmcnt(0)" ::: "memory");
    __syncthreads();
    if (s + 1 < nst) STAGE(db ^ 1, ca0 + (s + 1) * 4, cw0 + (s + 1) * 4);
    const int wi = lg * 512 + (wv * 16 + lr) * 8;
    bf16x8 whi = *(const bf16x8*)&st[db][2][wi];
    bf16x8 wlo;
    if (three) wlo = *(const bf16x8*)&st[db][3][wi];
#pragma unroll
    for (int rt = 0; rt < 4; ++rt) {
      const int ai = lg * 512 + (rt * 16 + lr) * 8;
      bf16x8 ahi = *(const bf16x8*)&st[db][0][ai];
      bf16x8 alo = *(const bf16x8*)&st[db][1][ai];
      acc[rt] = mf(ahi, whi, acc[rt]);
      acc[rt] = mf(alo, whi, acc[rt]);
      if (three) acc[rt] = mf(ahi, wlo, acc[rt]);
    }
    __syncthreads();
    db ^= 1;
  }

  // ---- gather per-thread tile: row = ln, cols wv*16..+15 ----
  const int row = ln;
  f32x4 t4[4];
  if (R.ksl > 1) {
    float* Pt = R.P + ((size_t)(sl * R.mtiles + mt) * R.npan + p) * 4096;
#pragma unroll
    for (int rt = 0; rt < 4; ++rt)
#pragma unroll
      for (int q = 0; q < 4; ++q)
        Pt[(rt * 16 + lg * 4 + q) * 64 + wv * 16 + lr] = acc[rt][q];
    __threadfence();
    __syncthreads();
    if (tid == 0) {
      int* cp = R.ctr + R.ctrb + mt * R.npan + p;
      int c = atomicAdd(cp, 1);
      int last = (c == R.ksl - 1);
      if (last) *cp = 0;
      islast = last;
    }
    __syncthreads();
    if (!islast) return;
    __threadfence();
#pragma unroll
    for (int u = 0; u < 4; ++u) t4[u] = f32x4{0.f, 0.f, 0.f, 0.f};
    for (int s2 = 0; s2 < R.ksl; ++s2) {
      const float* Pb = R.P + ((size_t)(s2 * R.mtiles + mt) * R.npan + p) * 4096 +
                        row * 64 + wv * 16;
#pragma unroll
      for (int u = 0; u < 4; ++u) t4[u] += *(const f32x4*)&Pb[u * 4];
    }
  } else {
#pragma unroll
    for (int rt = 0; rt < 4; ++rt)
#pragma unroll
      for (int q = 0; q < 4; ++q)
        LDSf[(rt * 16 + lg * 4 + q) * 68 + wv * 16 + lr] = acc[rt][q];
    __syncthreads();
#pragma unroll
    for (int u = 0; u < 4; ++u)
      t4[u] = *(const f32x4*)&LDSf[row * 68 + wv * 16 + u * 4];
  }

  if (R.ctype == 0) {
    const int colg = p * 64 + wv * 16;
    if (R.addC) {
      const float* ap = R.addC + (size_t)(mt * 64 + row) * R.ncF + colg;
#pragma unroll
      for (int u = 0; u < 4; ++u) t4[u] += *(const f32x4*)&ap[u * 4];
    }
    if (R.outF) {
      float* op = R.outF + (size_t)(mt * 64 + row) * R.ncF + colg;
#pragma unroll
      for (int u = 0; u < 4; ++u) *(f32x4*)&op[u * 4] = t4[u];
    }
    if (R.Zhi) {
#pragma unroll
      for (int u2 = 0; u2 < 2; ++u2) {
        float v[8];
#pragma unroll
        for (int e = 0; e < 4; ++e) { v[e] = t4[u2 * 2][e]; v[4 + e] = t4[u2 * 2 + 1][e]; }
        u16x8 hi, lo;
#pragma unroll
        for (int e = 0; e < 8; ++e) {
          u16 h = bf_rnd(v[e]);
          hi[e] = h;
          lo[e] = bf_rnd(v[e] - bf_val(h));
        }
        size_t zi = ((size_t)(R.zoff + p * 8 + wv * 2 + u2) * 64 + row) * 8;
        *(u16x8*)&R.Zhi[zi] = hi;
        *(u16x8*)&R.Zlo[zi] = lo;
      }
    }
  } else {
    // fused Wcat-top pack: W[(n2,a),(m2,k)] = sgf(a,a^k)*(diag - V2raw[n2,m2,a^k])
    const int n2g = mt * 64 + row;
#pragma unroll
    for (int u2 = 0; u2 < 2; ++u2) {
      float v[8];
#pragma unroll
      for (int e = 0; e < 4; ++e) { v[e] = t4[u2 * 2][e]; v[4 + e] = t4[u2 * 2 + 1][e]; }
      const int m2 = p * 8 + wv * 2 + u2;
#pragma unroll
      for (int k = 0; k < 8; ++k) {
        float val[8];
#pragma unroll
        for (int a = 0; a < 8; ++a) { int c = a ^ k; val[a] = sgf(a, c) * (-v[c]); }
        if (m2 == n2g) val[k] += 1.0f;
        u16x8 hi, lo;
#pragma unroll
        for (int e = 0; e < 8; ++e) {
          u16 h = bf_rnd(val[e]);
          hi[e] = h;
          lo[e] = bf_rnd(val[e] - bf_val(h));
        }
        size_t wi2 = ((size_t)(p * 768 + n2g) * 64 + (wv * 16 + u2 * 8 + k)) * 8;
        *(u16x8*)&R.Zhi[wi2] = hi;
        if (R.Zlo) *(u16x8*)&R.Zlo[wi2] = lo;
      }
    }
  }
}

// ---------------------------------------------------------------------------
// D1: pack inputs -> permuted/signed bf16 hi/lo operand buffers
// ---------------------------------------------------------------------------
__global__ __launch_bounds__(256) void pack_init(
    const float* __restrict__ x, const float* __restrict__ w1,
    const float* __restrict__ w2, u16* Ww1pHi, u16* Ww1pLo, u16* Aw1hi,
    u16* Aw1lo, u16* Aw2hi, u16* Aw2lo, u16* Axhi, u16* Axlo, u16* WcatHi,
    u16* WcatLo, u16* Z0hi, u16* Z0lo, float* out0, int* ctr) {
  int u = blockIdx.x * 256 + threadIdx.x;
  if (u < 1048576) {  // Ww1' = alpha*rev-perm(w1): rows (m,a), cols (n1,c')
    int cp = u & 7, n1 = (u >> 3) & 511, m = u >> 12;
    const float* wp = w1 + (size_t)m * 4096 + n1 * 8;
    float w[8];
#pragma unroll
    for (int c = 0; c < 8; ++c) w[c] = wp[c];
    int g = n1 * 8 + cp, pp = g >> 6, col = g & 63;
    u16x8 hi, lo;
#pragma unroll
    for (int a = 0; a < 8; ++a) {
      int c = a ^ cp;
      float v = ALPHA_F * sgr(a, c) * w[c];
      u16 h = bf_rnd(v);
      hi[a] = h;
      lo[a] = bf_rnd(v - bf_val(h));
    }
    size_t o = ((size_t)(pp * 256 + m) * 64 + col) * 8;
    *(u16x8*)&Ww1pHi[o] = hi;
    if (Ww1pLo) *(u16x8*)&Ww1pLo[o] = lo;
  } else if (u < 2097152) {  // Wcat bottom = alpha*rev-perm(w2): rows (n,a), cols (m2,k)
    int v_ = u - 1048576;
    int k = v_ & 7, m2 = (v_ >> 3) & 255, n = v_ >> 11;
    const float* wp = w2 + (size_t)n * 2048 + m2 * 8;
    float w[8];
#pragma unroll
    for (int c = 0; c < 8; ++c) w[c] = wp[c];
    int g = m2 * 8 + k, pp = g >> 6, col = g & 63;
    u16x8 hi, lo;
#pragma unroll
    for (int a = 0; a < 8; ++a) {
      int c = a ^ k;
      float v = ALPHA_F * sgr(a, c) * w[c];
      u16 h = bf_rnd(v);
      hi[a] = h;
      lo[a] = bf_rnd(v - bf_val(h));
    }
    size_t o = ((size_t)(pp * 768 + 256 + n) * 64 + col) * 8;
    *(u16x8*)&WcatHi[o] = hi;
    if (WcatLo) *(u16x8*)&WcatLo[o] = lo;
  } else if (u < 2228224) {  // Aw1[n,(m,a)] = w1[m,n,a]
    int v_ = u - 2097152;
    int m = v_ & 255, n = v_ >> 8;
    const float* wp = w1 + (size_t)m * 4096 + n * 8;
    u16x8 hi, lo;
#pragma unroll
    for (int a = 0; a < 8; ++a) {
      float v = wp[a];
      u16 h = bf_rnd(v);
      hi[a] = h;
      lo[a] = bf_rnd(v - bf_val(h));
    }
    size_t o = ((size_t)((n >> 6) * 256 + m) * 64 + (n & 63)) * 8;
    *(u16x8*)&Aw1hi[o] = hi;
    *(u16x8*)&Aw1lo[o] = lo;
  } else if (u < 2359296) {  // Aw2[n2,(m,a)] = w2[m,n2,a]
    int v_ = u - 2228224;
    int m = v_ & 511, n2 = v_ >> 9;
    const float* wp = w2 + (size_t)m * 2048 + n2 * 8;
    u16x8 hi, lo;
#pragma unroll
    for (int a = 0; a < 8; ++a) {
      float v = wp[a];
      u16 h = bf_rnd(v);
      hi[a] = h;
      lo[a] = bf_rnd(v - bf_val(h));
    }
    size_t o = ((size_t)((n2 >> 6) * 512 + m) * 64 + (n2 & 63)) * 8;
    *(u16x8*)&Aw2hi[o] = hi;
    *(u16x8*)&Aw2lo[o] = lo;
  } else if (u < 2375680) {  // Ax split
    int v_ = u - 2359296;
    int m = v_ & 255, b = v_ >> 8;
    const float* wp = x + (size_t)b * 2048 + m * 8;
    u16x8 hi, lo;
#pragma unroll
    for (int a = 0; a < 8; ++a) {
      float v = wp[a];
      u16 h = bf_rnd(v);
      hi[a] = h;
      lo[a] = bf_rnd(v - bf_val(h));
    }
    size_t o = ((size_t)m * 64 + b) * 8;
    *(u16x8*)&Axhi[o] = hi;
    *(u16x8*)&Axlo[o] = lo;
  } else if (u < 2408448) {  // out0 = x
    int v_ = u - 2375680;
    ((float4*)out0)[v_] = ((const float4*)x)[v_];
  } else if (u < 2441216) {  // Z0 S2-slice = 0
    int v_ = u - 2408448;
    u16x8 z = {0, 0, 0, 0, 0, 0, 0, 0};
    if (v_ < 16384) *(u16x8*)&Z0hi[(size_t)v_ * 8] = z;
    else *(u16x8*)&Z0lo[(size_t)(v_ - 16384) * 8] = z;
  } else if (u < 2441312) {
    ctr[u - 2441216] = 0;
  }
}

// ---------------------------------------------------------------------------
// D3: W1~[(n,a),(n1,k)] = sgf(a,a^k)*(diag - V1raw[n,n1,a^k]), split hi/lo
// ---------------------------------------------------------------------------
__global__ __launch_bounds__(256) void pack_w1k(const float* __restrict__ V1,
                                                u16* W1hi, u16* W1lo) {
  int u = blockIdx.x * 256 + threadIdx.x;  // 2M = 64p x 512n x 64col
  int col = u & 63, n = (u >> 6) & 511, pp = u >> 15;
  int n1 = pp * 8 + (col >> 3), k = col & 7;
  const float* vp = V1 + (size_t)n * 4096 + n1 * 8;
  float v[8];
#pragma unroll
  for (int c = 0; c < 8; ++c) v[c] = vp[c];
  u16x8 hi, lo;
#pragma unroll
  for (int a = 0; a < 8; ++a) {
    int c = a ^ k;
    float val = sgf(a, c) * (-v[c]);
    if (n == n1 && a == k) val += 1.0f;
    u16 h = bf_rnd(val);
    hi[a] = h;
    lo[a] = bf_rnd(val - bf_val(h));
  }
  size_t o = ((size_t)(pp * 512 + n) * 64 + col) * 8;
  *(u16x8*)&W1hi[o] = hi;
  if (W1lo) *(u16x8*)&W1lo[o] = lo;
}

extern "C" void kernel_launch(void* const* d_in, const int* in_sizes, int n_in,
                              void* d_out, int out_size, void* d_ws,
                              size_t ws_size, hipStream_t stream) {
  const float* x = (const float*)d_in[0];   // (64,256,8)
  const float* w1 = (const float*)d_in[1];  // (256,512,8)
  const float* w2 = (const float*)d_in[2];  // (512,256,8)

  float* out0 = (float*)d_out;
  float* out1 = out0 + 131072;
  float* out2 = out1 + 262144;

  char* W = (char*)d_ws;
  const size_t MB = 1ull << 20;
  const bool full = ws_size >= 125 * MB;

  u16 *W1hi, *W1lo, *WcatHi, *WcatLo, *Ww1pHi, *Ww1pLo;
  u16 *Aw1hi, *Aw1lo, *Aw2hi, *Aw2lo, *Axhi, *Axlo, *Z0hi, *Z0lo, *Z1hi, *Z1lo;
  float *V1raw, *P1, *P2, *c1;
  int* ctr;
  if (full) {
    W1hi = (u16*)W;              W1lo = (u16*)(W + 32 * MB);   // written D3 (alias below)
    Ww1pHi = (u16*)W;            Ww1pLo = (u16*)(W + 16 * MB); // dead after D2
    Aw1hi = (u16*)(W + 32 * MB); Aw1lo = (u16*)(W + 34 * MB);
    Aw2hi = (u16*)(W + 36 * MB); Aw2lo = (u16*)(W + 38 * MB);
    Axhi = (u16*)(W + 40 * MB);  Axlo = (u16*)(W + 40 * MB + 262144);
    WcatHi = (u16*)(W + 64 * MB); WcatLo = (u16*)(W + 88 * MB);
    V1raw = (float*)(W + 112 * MB);
    P1 = (float*)(W + 112 * MB); P2 = (float*)(W + 116 * MB);  // live only in mains
    c1 = (float*)(W + 120 * MB);
    Z0hi = (u16*)(W + 121 * MB);
  } else {  // degraded 2-pass tier (no W-lo planes), ~68 MB
    W1hi = (u16*)W;              W1lo = nullptr;
    Ww1pHi = (u16*)W;            Ww1pLo = nullptr;
    Aw1hi = (u16*)(W + 16 * MB); Aw1lo = (u16*)(W + 18 * MB);
    Aw2hi = (u16*)(W + 20 * MB); Aw2lo = (u16*)(W + 22 * MB);
    Axhi = (u16*)(W + 24 * MB);  Axlo = (u16*)(W + 24 * MB + 262144);
    WcatHi = (u16*)(W + 32 * MB); WcatLo = nullptr;
    V1raw = (float*)(W + 56 * MB);
    P1 = (float*)(W + 56 * MB);  P2 = (float*)(W + 60 * MB);
    c1 = (float*)(W + 64 * MB);
    Z0hi = (u16*)(W + 65 * MB);
  }
  Z0lo = Z0hi + 393216;
  Z1hi = Z0hi + 786432;
  Z1lo = Z0hi + 1179648;
  ctr = (int*)(Z0hi + 1572864);

  // D1: pack
  pack_init<<<9537, 256, 0, stream>>>(x, w1, w2, Ww1pHi, Ww1pLo, Aw1hi, Aw1lo,
                                      Aw2hi, Aw2lo, Axhi, Axlo, WcatHi, WcatLo,
                                      Z0hi, Z0lo, out0, ctr);

  // D2: {compose1 -> V1raw, compose2 -> Wcat-top (fused pack), c1 -> c1buf + Z0.S1}
  Role rco1{}, rco2{}, rc1{};
  rco1.Ahi = Aw1hi; rco1.Alo = Aw1lo; rco1.Whi = Ww1pHi; rco1.Wlo = Ww1pLo;
  rco1.P = P1; rco1.ctr = ctr; rco1.Zhi = nullptr; rco1.Zlo = nullptr;
  rco1.outF = V1raw; rco1.addC = nullptr;
  rco1.kchA = 256; rco1.pstr = 256; rco1.mtiles = 8; rco1.npan = 64;
  rco1.ksl = 1; rco1.kcpsl = 256; rco1.zoff = 0; rco1.ncF = 4096;
  rco1.ctype = 0; rco1.ctrb = 0;

  rco2.Ahi = Aw2hi; rco2.Alo = Aw2lo;
  rco2.Whi = WcatHi + (size_t)256 * 512;
  rco2.Wlo = WcatLo ? WcatLo + (size_t)256 * 512 : nullptr;
  rco2.P = P1; rco2.ctr = ctr; rco2.Zhi = WcatHi; rco2.Zlo = WcatLo;
  rco2.outF = nullptr; rco2.addC = nullptr;
  rco2.kchA = 512; rco2.pstr = 768; rco2.mtiles = 4; rco2.npan = 32;
  rco2.ksl = 1; rco2.kcpsl = 512; rco2.zoff = 0; rco2.ncF = 2048;
  rco2.ctype = 1; rco2.ctrb = 0;

  rc1.Ahi = Axhi; rc1.Alo = Axlo; rc1.Whi = Ww1pHi; rc1.Wlo = Ww1pLo;
  rc1.P = P1; rc1.ctr = ctr; rc1.Zhi = Z0hi; rc1.Zlo = Z0lo;
  rc1.outF = c1; rc1.addC = nullptr;
  rc1.kchA = 256; rc1.pstr = 256; rc1.mtiles = 1; rc1.npan = 64;
  rc1.ksl = 1; rc1.kcpsl = 256; rc1.zoff = 256; rc1.ncF = 4096;
  rc1.ctype = 0; rc1.ctrb = 0;

  gemm3<<<704, 256, 0, stream>>>(rco1, rco2, rc1, 512, 128);

  // D3: pack W1~
  pack_w1k<<<8192, 256, 0, stream>>>(V1raw, W1hi, W1lo);

  // base roles for main loop
  Role g2{}, g1{};
  g2.Whi = WcatHi; g2.Wlo = WcatLo; g2.P = P2; g2.ctr = ctr;
  g2.outF = nullptr; g2.addC = nullptr;
  g2.kchA = 768; g2.pstr = 768; g2.mtiles = 1; g2.npan = 32;
  g2.ksl = 6; g2.kcpsl = 128; g2.zoff = 0; g2.ncF = 2048; g2.ctype = 0;
  g2.ctrb = 64;

  g1.Whi = W1hi; g1.Wlo = W1lo; g1.P = P1; g1.ctr = ctr;
  g1.addC = c1;
  g1.kchA = 512; g1.pstr = 512; g1.mtiles = 1; g1.npan = 64;
  g1.ksl = 4; g1.kcpsl = 128; g1.zoff = 256; g1.ncF = 4096; g1.ctype = 0;
  g1.ctrb = 0;

  // D4..D22: t = 0..18, each = {g2_t, g1_{t+1}} (independent, same Zcur)
  for (int t = 0; t < 19; ++t) {
    u16* ZcH = (t & 1) ? Z1hi : Z0hi;
    u16* ZcL = (t & 1) ? Z1lo : Z0lo;
    u16* ZnH = (t & 1) ? Z0hi : Z1hi;
    u16* ZnL = (t & 1) ? Z0lo : Z1lo;
    Role a = g2;
    a.Ahi = ZcH; a.Alo = ZcL; a.Zhi = ZnH; a.Zlo = ZnL;
    Role b = g1;
    b.Ahi = ZcH + 131072; b.Alo = ZcL + 131072;  // S1 slice (chunk 256)
    b.Zhi = ZnH; b.Zlo = ZnL;
    b.outF = (t == 18) ? out1 : nullptr;
    gemm3<<<448, 256, 0, stream>>>(a, b, b, 192, 256);
  }

  // D23: final g2 reads Z1 = [S2_19 | S1_20] -> out2
  Role f = g2;
  f.Ahi = Z1hi; f.Alo = Z1lo; f.Zhi = nullptr; f.Zlo = nullptr;
  f.outF = out2;
  gemm3<<<192, 256, 0, stream>>>(f, f, f, 192, 0);
}

// Round 4
// 1584.629 us; speedup vs baseline: 4.2048x; 1.2122x over previous
//
#include <hip/hip_runtime.h>

typedef unsigned short u16;
typedef __attribute__((ext_vector_type(4))) float f32x4;
typedef __attribute__((ext_vector_type(8))) __bf16 bf16x8;
typedef __attribute__((ext_vector_type(8))) u16 u16x8;
typedef __attribute__((ext_vector_type(4))) unsigned int u32x4;

#define ALPHA_F 0.1f

// Cl(3,0): e_a * e_c = (-1)^p e_{a^c}, p = (c0&(a1^a2)) ^ (c1&a2)  [R1-R3 verified]
__device__ __host__ constexpr bool SGN(int a, int c) {
  return ((((c & 1) & (((a >> 1) ^ (a >> 2)) & 1)) ^
           (((c >> 1) & 1) & ((a >> 2) & 1))) != 0);
}
__device__ __host__ constexpr float REVF(int c) {
  const int r = (c & 1) + ((c >> 1) & 1) + ((c >> 2) & 1);
  return (r >= 2) ? -1.f : 1.f;
}
__device__ __forceinline__ u16 bf_rnd(float f) {
  unsigned u = __float_as_uint(f);
  return (u16)((u + 0x7FFFu + ((u >> 16) & 1u)) >> 16);
}
__device__ __forceinline__ float bf_val(u16 h) {
  return __uint_as_float(((unsigned)h) << 16);
}
__device__ __forceinline__ f32x4 mf(bf16x8 a, bf16x8 b, f32x4 c) {
  return __builtin_amdgcn_mfma_f32_16x16x32_bf16(a, b, c, 0, 0, 0);
}

// ---------------------------------------------------------------------------
// Blade-plane GEMM: out[b(64·nrb), col, k] = sum_c sg(k^c,c)·A_{k^c} @ V_c
//  A planes:  [8][AR][AN] bf16 hi/lo (global, frag-loaded directly)
//  V packed:  [pan][ksl*4 chunks][hl2][c8][lg4][m16][e8] u16 (16KB/chunk)
//  3-pass split: Ahi*Vhi + Alo*Vhi + Ahi*Vlo, fp32 acc. K-split over slices
//  (4 chunks of 32 each), counter-gated last-block reduce; epilogues:
//  Z-state write (bf16 hi/lo planes), fp32 [b][NC][k], fp32 [row][NC][k],
//  P-native fp32 (c1), optional P-native add (c1).
// ---------------------------------------------------------------------------
struct Role {
  const u16 *Ahi, *Alo;
  const u16* Vpk;
  float* P;
  int* ctr;
  const float* addP;
  u16 *Zhi, *Zlo;
  float *outBMK, *outRaw, *outP;
  int AR, AN, acol0, npan, ksl, NC, zcol0, ctrb;
};

__global__ __launch_bounds__(256) void pgemm(Role r0, Role r1, Role r2,
                                             int n0, int n01) {
  __shared__ u16 Vs[2][16384];  // [dbuf][hl][c][s][lg][m][e] = 32KB each
  __shared__ int islast;

  Role R;
  int r;
  const int bid = blockIdx.x;
  if (bid < n0) { R = r0; r = bid; }
  else if (bid < n01) { R = r1; r = bid - n0; }
  else { R = r2; r = bid - n01; }

  const int tid = threadIdx.x;
  const int w = tid >> 6, l = tid & 63;
  const int lg = l >> 4, lm = l & 15;

  const int sl = r % R.ksl;
  const int slot = r / R.ksl;
  const int p = slot % R.npan;
  const int rb = slot / R.npan;
  const int rowg = rb * 64 + w * 16 + lm;
  const int nchtot = R.ksl * 4;

  f32x4 acc[8];
#pragma unroll
  for (int i = 0; i < 8; ++i) acc[i] = f32x4{0.f, 0.f, 0.f, 0.f};

  auto VSTAGE = [&](int db, int ch) {
    const u16* src = R.Vpk + ((size_t)p * nchtot + sl * 4 + ch) * 8192;
#pragma unroll
    for (int i = 0; i < 4; ++i) {
      const int g = tid * 4 + i;  // [hl][c][lg][m]
      const u32x4 v = *(const u32x4*)(src + (size_t)g * 8);
      u16* d = &Vs[db][(g >> 9) * 8192 + ((g >> 6) & 7) * 1024 +
                       ((g >> 4) & 3) * 128 + (g & 15) * 8];
      *(u32x4*)d = v;
      *(u32x4*)(d + 512) = v ^ 0x80008000u;  // negated sign-plane
    }
  };
  auto ALOAD = [&](bf16x8* h, bf16x8* lo2, int ch) {
    const int coff = R.acol0 + (sl * 4 + ch) * 32 + lg * 8;
#pragma unroll
    for (int a = 0; a < 8; ++a) {
      const size_t o = ((size_t)(a * R.AR + rowg)) * R.AN + coff;
      h[a] = *(const bf16x8*)(R.Ahi + o);
      lo2[a] = *(const bf16x8*)(R.Alo + o);
    }
  };
  auto COMPUTE = [&](int db, const bf16x8* h, const bf16x8* lo2) {
    const int fb = lg * 128 + lm * 8;
#pragma unroll
    for (int c = 0; c < 8; ++c) {
      const bf16x8 vhp = *(const bf16x8*)&Vs[db][fb + c * 1024];
      const bf16x8 vhn = *(const bf16x8*)&Vs[db][fb + c * 1024 + 512];
      const bf16x8 vlp = *(const bf16x8*)&Vs[db][fb + 8192 + c * 1024];
      const bf16x8 vln = *(const bf16x8*)&Vs[db][fb + 8192 + c * 1024 + 512];
#pragma unroll
      for (int a = 0; a < 8; ++a) {
        const int k = a ^ c;
        const bf16x8 vh = SGN(a, c) ? vhn : vhp;
        const bf16x8 vl = SGN(a, c) ? vln : vlp;
        acc[k] = mf(h[a], vh, acc[k]);
        acc[k] = mf(lo2[a], vh, acc[k]);
        acc[k] = mf(h[a], vl, acc[k]);
      }
    }
  };

  bf16x8 Ah[8], Al8[8], Bh[8], Bl[8];
  VSTAGE(0, 0); ALOAD(Ah, Al8, 0);
  __syncthreads();
  VSTAGE(1, 1); ALOAD(Bh, Bl, 1);
  COMPUTE(0, Ah, Al8);
  __syncthreads();
  VSTAGE(0, 2); ALOAD(Ah, Al8, 2);
  COMPUTE(1, Bh, Bl);
  __syncthreads();
  VSTAGE(1, 3); ALOAD(Bh, Bl, 3);
  COMPUTE(0, Ah, Al8);
  __syncthreads();
  COMPUTE(1, Bh, Bl);

  // ---- P partial write (MFMA-native flat layout) ----
  float* Ps = R.P + ((size_t)slot * R.ksl + sl) * 8192;
#pragma unroll
  for (int k = 0; k < 8; ++k)
    *(f32x4*)&Ps[(size_t)((w * 8 + k) * 64 + l) * 4] = acc[k];

  __threadfence();
  __syncthreads();
  if (tid == 0) {
    int* cp = &R.ctr[R.ctrb + slot];
    const int c = atomicAdd(cp, 1);
    const int last = (c == R.ksl - 1);
    if (last) *cp = 0;
    islast = last;
  }
  __syncthreads();
  if (!islast) return;
  __threadfence();

  // ---- deterministic reduce (fixed slice order), c1 pre-add ----
  const int idx0 = tid * 8;
  f32x4 s4[8];
  {
    const float* cb = R.addP ? R.addP + (size_t)p * 8192 + (size_t)idx0 * 4 : nullptr;
#pragma unroll
    for (int u = 0; u < 8; ++u)
      s4[u] = cb ? *(const f32x4*)&cb[u * 4] : f32x4{0.f, 0.f, 0.f, 0.f};
  }
  const float* Pb = R.P + (size_t)slot * R.ksl * 8192;
  for (int ss = 0; ss < R.ksl; ++ss) {
    const float* q = Pb + (size_t)ss * 8192 + (size_t)idx0 * 4;
#pragma unroll
    for (int u = 0; u < 8; ++u) s4[u] += *(const f32x4*)&q[u * 4];
  }

  const int kk = (idx0 >> 6) & 7, bt = idx0 >> 9, ln0 = idx0 & 63;
  const int lg0 = ln0 >> 4, m0 = ln0 & 15;

  if (R.outP) {
    float* op = R.outP + (size_t)p * 8192 + (size_t)idx0 * 4;
#pragma unroll
    for (int u = 0; u < 8; ++u) *(f32x4*)&op[u * 4] = s4[u];
  }
  if (R.Zhi) {
#pragma unroll
    for (int q2 = 0; q2 < 4; ++q2) {
      const int b = bt * 16 + lg0 * 4 + q2;
      u16x8 h8, l8;
#pragma unroll
      for (int u = 0; u < 8; ++u) {
        const float v = s4[u][q2];
        const u16 hh = bf_rnd(v);
        h8[u] = hh;
        l8[u] = bf_rnd(v - bf_val(hh));
      }
      const size_t zo = ((size_t)kk * 64 + b) * 768 + R.zcol0 + p * 16 + m0;
      *(u16x8*)&R.Zhi[zo] = h8;
      *(u16x8*)&R.Zlo[zo] = l8;
    }
  }
  if (R.outBMK) {
#pragma unroll
    for (int q2 = 0; q2 < 4; ++q2) {
      const int b = bt * 16 + lg0 * 4 + q2;
#pragma unroll
      for (int u = 0; u < 8; ++u)
        R.outBMK[((size_t)b * R.NC + p * 16 + m0 + u) * 8 + kk] = s4[u][q2];
    }
  }
  if (R.outRaw) {
#pragma unroll
    for (int q2 = 0; q2 < 4; ++q2) {
      const int row = rb * 64 + bt * 16 + lg0 * 4 + q2;
#pragma unroll
      for (int u = 0; u < 8; ++u)
        R.outRaw[((size_t)row * R.NC + p * 16 + m0 + u) * 8 + kk] = s4[u][q2];
    }
  }
}

// ---------------------------------------------------------------------------
// D1: pack raw inputs -> compose operands, Wcat-bottom, x-planes, out0, Z0-S2=0
// ---------------------------------------------------------------------------
__global__ __launch_bounds__(256) void pack_in(
    const float* __restrict__ x, const float* __restrict__ w1,
    const float* __restrict__ w2, u16* P1h, u16* P1l, u16* Q1, u16* Qc1,
    u16* P2h, u16* P2l, u16* Q2, u16* Wcat, u16* Axh, u16* Axl, u16* Z0h,
    u16* Z0l, float* out0, int* ctr) {
  const int t = blockIdx.x * 256 + threadIdx.x;
  if (t < 131072) {  // w1-space: r in [0,256) rows, cc in [0,512) cols
    const int r = t >> 9, cc = t & 511;
    const float* s = w1 + ((size_t)r * 512 + cc) * 8;
    float v[8];
#pragma unroll
    for (int c = 0; c < 8; ++c) v[c] = s[c];
#pragma unroll
    for (int a = 0; a < 8; ++a) {  // P1 planes [a][n=cc][m=r]
      const u16 h = bf_rnd(v[a]);
      P1h[((size_t)a * 512 + cc) * 256 + r] = h;
      P1l[((size_t)a * 512 + cc) * 256 + r] = bf_rnd(v[a] - bf_val(h));
    }
    const size_t ob = (size_t)((cc >> 4) * 8 + (r >> 5)) * 8192 +
                      ((r >> 3) & 3) * 128 + (cc & 15) * 8 + (r & 7);
#pragma unroll
    for (int c = 0; c < 8; ++c) {
      const float q1 = REVF(c) * v[c];  // compose1 V-side: REV*w1
      u16 h = bf_rnd(q1);
      Q1[ob + c * 512] = h;
      Q1[ob + 4096 + c * 512] = bf_rnd(q1 - bf_val(h));
      const float qc = ALPHA_F * q1;    // c1 V-side: a*REV*w1
      h = bf_rnd(qc);
      Qc1[ob + c * 512] = h;
      Qc1[ob + 4096 + c * 512] = bf_rnd(qc - bf_val(h));
    }
  } else if (t < 262144) {  // w2-space: r in [0,512), c2 in [0,256)
    const int u = t - 131072;
    const int r = u >> 8, c2 = u & 255;
    const float* s = w2 + ((size_t)r * 256 + c2) * 8;
    float v[8];
#pragma unroll
    for (int c = 0; c < 8; ++c) v[c] = s[c];
#pragma unroll
    for (int a = 0; a < 8; ++a) {  // P2 planes [a][n2=c2][m=r]
      const u16 h = bf_rnd(v[a]);
      P2h[((size_t)a * 256 + c2) * 512 + r] = h;
      P2l[((size_t)a * 256 + c2) * 512 + r] = bf_rnd(v[a] - bf_val(h));
    }
    const size_t ob2 = (size_t)((c2 >> 4) * 16 + (r >> 5)) * 8192 +
                       ((r >> 3) & 3) * 128 + (c2 & 15) * 8 + (r & 7);
    const size_t obW = (size_t)((c2 >> 4) * 24 + 8 + (r >> 5)) * 8192 +
                       ((r >> 3) & 3) * 128 + (c2 & 15) * 8 + (r & 7);
#pragma unroll
    for (int c = 0; c < 8; ++c) {
      const float q2 = REVF(c) * v[c];  // compose2 V-side
      u16 h = bf_rnd(q2);
      Q2[ob2 + c * 512] = h;
      Q2[ob2 + 4096 + c * 512] = bf_rnd(q2 - bf_val(h));
      const float qw = ALPHA_F * q2;    // Wcat bottom rows (256..767)
      h = bf_rnd(qw);
      Wcat[obW + c * 512] = h;
      Wcat[obW + 4096 + c * 512] = bf_rnd(qw - bf_val(h));
    }
  } else if (t < 278528) {  // x planes [a][b][n]
    const int u = t - 262144;
    const int b = u >> 8, n = u & 255;
    const float* s = x + ((size_t)b * 256 + n) * 8;
#pragma unroll
    for (int a = 0; a < 8; ++a) {
      const u16 h = bf_rnd(s[a]);
      Axh[((size_t)a * 64 + b) * 256 + n] = h;
      Axl[((size_t)a * 64 + b) * 256 + n] = bf_rnd(s[a] - bf_val(h));
    }
  } else if (t < 311296) {  // out0 = x
    const int u = t - 278528;
    ((float4*)out0)[u] = ((const float4*)x)[u];
  } else if (t < 344064) {  // Z0 S2-slab zero (cols 0..255)
    const int u = t - 311296;
    const int hl = u >> 14, idx = u & 16383;
    u16* Z = hl ? Z0l : Z0h;
    const size_t o = (size_t)(idx >> 5) * 768 + (idx & 31) * 8;
    const u16x8 z = {0, 0, 0, 0, 0, 0, 0, 0};
    *(u16x8*)&Z[o] = z;
  } else if (t < 344576) {
    ctr[t - 344064] = 0;
  }
}

// ---------------------------------------------------------------------------
// D3: pack composed operators -> main-loop V panels (I - a*V), split hi/lo
// ---------------------------------------------------------------------------
__global__ __launch_bounds__(256) void pack_ops(const float* __restrict__ V1raw,
                                                const float* __restrict__ V2raw,
                                                u16* Vpk1, u16* Wcat) {
  const int t = blockIdx.x * 256 + threadIdx.x;
  if (t < 262144) {  // V1~: n,m in [0,512)
    const int n = t >> 9, m = t & 511;
    const float* s = V1raw + ((size_t)n * 512 + m) * 8;
    const size_t ob = (size_t)((m >> 4) * 16 + (n >> 5)) * 8192 +
                      ((n >> 3) & 3) * 128 + (m & 15) * 8 + (n & 7);
#pragma unroll
    for (int c = 0; c < 8; ++c) {
      const float val = ((c == 0) && (n == m) ? 1.0f : 0.0f) - ALPHA_F * s[c];
      const u16 h = bf_rnd(val);
      Vpk1[ob + c * 512] = h;
      Vpk1[ob + 4096 + c * 512] = bf_rnd(val - bf_val(h));
    }
  } else if (t < 327680) {  // Wcat top rows (0..255): n2,j in [0,256)
    const int u = t - 262144;
    const int n2 = u >> 8, j = u & 255;
    const float* s = V2raw + ((size_t)n2 * 256 + j) * 8;
    const size_t ob = (size_t)((j >> 4) * 24 + (n2 >> 5)) * 8192 +
                      ((n2 >> 3) & 3) * 128 + (j & 15) * 8 + (n2 & 7);
#pragma unroll
    for (int c = 0; c < 8; ++c) {
      const float val = ((c == 0) && (n2 == j) ? 1.0f : 0.0f) - ALPHA_F * s[c];
      const u16 h = bf_rnd(val);
      Wcat[ob + c * 512] = h;
      Wcat[ob + 4096 + c * 512] = bf_rnd(val - bf_val(h));
    }
  }
}

extern "C" void kernel_launch(void* const* d_in, const int* in_sizes, int n_in,
                              void* d_out, int out_size, void* d_ws,
                              size_t ws_size, hipStream_t stream) {
  const float* x = (const float*)d_in[0];   // (64,256,8)
  const float* w1 = (const float*)d_in[1];  // (256,512,8)
  const float* w2 = (const float*)d_in[2];  // (512,256,8)

  float* out0 = (float*)d_out;
  float* out1 = out0 + 131072;
  float* out2 = out1 + 262144;

  char* W = (char*)d_ws;
  const size_t MB = 1ull << 20;
  u16* Vpk1 = (u16*)(W);                     // 8 MB  (32p x 16ch x 16KB)
  u16* Wcat = (u16*)(W + 8 * MB);            // 6 MB  (16p x 24ch)
  u16* Q1 = (u16*)(W + 14 * MB);             // 4 MB  (32p x 8ch)
  u16* Q2 = (u16*)(W + 18 * MB);             // 4 MB  (16p x 16ch)
  u16* Qc1 = (u16*)(W + 22 * MB);            // 4 MB  (32p x 8ch)
  u16* P1h = (u16*)(W + 26 * MB);            // 2 MB
  u16* P1l = (u16*)(W + 28 * MB);
  u16* P2h = (u16*)(W + 30 * MB);
  u16* P2l = (u16*)(W + 32 * MB);
  u16* Axh = (u16*)(W + 34 * MB);            // 256 KB
  u16* Axl = (u16*)(W + 34 * MB + 262144);
  float* c1P = (float*)(W + 34 * MB + 524288);  // 1 MB (32 panels x 32KB)
  float* V1raw = (float*)(W + 35 * MB + 524288);  // 8 MB
  float* V2raw = (float*)(W + 43 * MB + 524288);  // 2 MB
  u16* Z0h = (u16*)(W + 45 * MB + 524288);   // 768 KB each
  u16* Z0l = Z0h + 393216;
  u16* Z1h = Z0h + 786432;
  u16* Z1l = Z0h + 1179648;
  int* ctr = (int*)(Z0h + 1572864);          // 512 ints
  float* Parena = (float*)(W + 49 * MB);     // 26 MB

  // D1: pack inputs
  pack_in<<<1346, 256, 0, stream>>>(x, w1, w2, P1h, P1l, Q1, Qc1, P2h, P2l, Q2,
                                    Wcat, Axh, Axl, Z0h, Z0l, out0, ctr);

  // D2: compose {V1, V2, c1} in one dispatch
  Role co1{};
  co1.Ahi = P1h; co1.Alo = P1l; co1.Vpk = Q1; co1.P = Parena; co1.ctr = ctr;
  co1.outRaw = V1raw;
  co1.AR = 512; co1.AN = 256; co1.acol0 = 0; co1.npan = 32; co1.ksl = 2;
  co1.NC = 512; co1.zcol0 = 0; co1.ctrb = 0;

  Role co2{};
  co2.Ahi = P2h; co2.Alo = P2l; co2.Vpk = Q2;
  co2.P = (float*)(W + 65 * MB); co2.ctr = ctr;
  co2.outRaw = V2raw;
  co2.AR = 256; co2.AN = 512; co2.acol0 = 0; co2.npan = 16; co2.ksl = 4;
  co2.NC = 256; co2.zcol0 = 0; co2.ctrb = 256;

  Role rc1{};
  rc1.Ahi = Axh; rc1.Alo = Axl; rc1.Vpk = Qc1;
  rc1.P = (float*)(W + 73 * MB); rc1.ctr = ctr;
  rc1.Zhi = Z0h; rc1.Zlo = Z0l; rc1.outP = c1P;
  rc1.AR = 64; rc1.AN = 256; rc1.acol0 = 0; rc1.npan = 32; rc1.ksl = 2;
  rc1.NC = 512; rc1.zcol0 = 256; rc1.ctrb = 320;

  pgemm<<<832, 256, 0, stream>>>(co1, co2, rc1, 512, 768);

  // D3: pack main operators
  pack_ops<<<1280, 256, 0, stream>>>(V1raw, V2raw, Vpk1, Wcat);

  // D4..D22: pair dispatches t=0..18: {g1: S1_{t+2}, g2: S2_{t+1}}
  for (int t = 0; t < 19; ++t) {
    u16* ZcH = (t & 1) ? Z1h : Z0h;
    u16* ZcL = (t & 1) ? Z1l : Z0l;
    u16* ZnH = (t & 1) ? Z0h : Z1h;
    u16* ZnL = (t & 1) ? Z0l : Z1l;

    Role g1{};
    g1.Ahi = ZcH; g1.Alo = ZcL; g1.Vpk = Vpk1; g1.P = Parena; g1.ctr = ctr;
    g1.addP = c1P; g1.Zhi = ZnH; g1.Zlo = ZnL;
    g1.outBMK = (t == 18) ? out1 : nullptr;
    g1.AR = 64; g1.AN = 768; g1.acol0 = 256; g1.npan = 32; g1.ksl = 4;
    g1.NC = 512; g1.zcol0 = 256; g1.ctrb = 0;

    Role g2{};
    g2.Ahi = ZcH; g2.Alo = ZcL; g2.Vpk = Wcat;
    g2.P = (float*)(W + 53 * MB); g2.ctr = ctr;
    g2.Zhi = ZnH; g2.Zlo = ZnL;
    g2.AR = 64; g2.AN = 768; g2.acol0 = 0; g2.npan = 16; g2.ksl = 6;
    g2.NC = 256; g2.zcol0 = 0; g2.ctrb = 32;

    pgemm<<<224, 256, 0, stream>>>(g1, g2, g2, 128, 224);
  }

  // D23: final g2 reads Z1 = [S2_19 | S1_20] -> out2 = S2_20
  Role gf{};
  gf.Ahi = Z1h; gf.Alo = Z1l; gf.Vpk = Wcat;
  gf.P = (float*)(W + 53 * MB); gf.ctr = ctr;
  gf.outBMK = out2;
  gf.AR = 64; gf.AN = 768; gf.acol0 = 0; gf.npan = 16; gf.ksl = 6;
  gf.NC = 256; gf.zcol0 = 0; gf.ctrb = 32;
  pgemm<<<96, 256, 0, stream>>>(gf, gf, gf, 96, 96);
}